// Round 12
// baseline (452.796 us; speedup 1.0000x reference)
//
#include <hip/hip_runtime.h>
#include <stdint.h>

// WARP loss, B=1024, Y=50000. inputs: input_ f32[B*Y], target f32[B*Y],
// max_num_trials i32[1]; output f32[1] = sum of per-row losses.
//
// Exact-RNG reduction (absmax 0.0 verified on HW, 8 runs): first violator in
// the random permutation == violator with min (u_bits>>9, col); num_trials-1
// == rank == #{cols != pos with key < kstar}.
//
// R12 = R5's two-kernel shape (measured best gen: 147us wall on the 120us
// VALU-issue floor; fine-grained 9216 blocks -> ~3% tail quantization vs the
// ~45us tail of the 1024-block single-kernel shape) + finish widened from
// 1 wave/row to 1 block(256)/row for 4x memory-level parallelism on the
// scattered candidate gathers. gen verbatim from R5; resolve body is R8's
// verified block-tree version reading the global candidate list; fallback
// and last-block done-ticket reduce (EXACT original summation order)
// unchanged from verified kernels.
#define BN 1024
#define YN 50000
#define SEGS 8              // threefry segments per row
#define SEGLEN 6250         // YN / SEGS
#define CAP_BIG 1024        // THR=2^25: E~390/row, sigma~20 -> never overflows
#define CAP_SMALL 192       // THR=2^23 legacy sizing (ws-constrained path)
#define LCAP 256            // per-block LDS candidate buffer (E~49, sigma~7)

// ---------------- rotl: single v_alignbit_b32 -------------------------------
#if defined(__has_builtin)
#  if __has_builtin(__builtin_amdgcn_alignbit)
#    define ROTL(x, r) __builtin_amdgcn_alignbit((x), (x), 32u - (r))
#  endif
#endif
#ifndef ROTL
#  define ROTL(x, r) (((x) << (r)) | ((x) >> (32 - (r))))
#endif

// ---------------- Threefry-2x32, key (0,42), counter (0, i) -----------------
// tf_core(v) == verified tf_bits(ctr) with v = ctr + 42 (round 1 specialized
// for x0_init == ks0 == 0).
#define TFR(r) { x0 += x1; x1 = ROTL(x1, r) ^ x0; }

__device__ __forceinline__ uint32_t tf_core(uint32_t v) {
    const uint32_t ks1 = 42u;
    const uint32_t ks2 = 0x1BD11BDAu ^ 42u;
    uint32_t x0 = v;
    uint32_t x1 = (ROTL(v, 13u)) ^ v;
    TFR(15u) TFR(26u) TFR(6u)
    x0 += ks1; x1 += ks2 + 1u;
    TFR(17u) TFR(29u) TFR(16u) TFR(24u)
    x0 += ks2; x1 += 2u;                  // ks0 == 0
    TFR(13u) TFR(15u) TFR(26u) TFR(6u)
    /* x0 += ks0 */ x1 += ks1 + 3u;
    TFR(17u) TFR(29u) TFR(16u) TFR(24u)
    x0 += ks1; x1 += ks2 + 4u;
    TFR(13u) TFR(15u) TFR(26u) TFR(6u)
    x0 += ks2; x1 += 5u;                  // ks0 == 0
    return x0 ^ x1;
}

// ws layout (4B units):
//   cnt[BN]      @ 0      \  zeroed by in-graph memset (8 KB)
//   done(+pad)   @ BN     /
//   pos[BN]      @ 2*BN
//   ps[BN]       @ 3*BN
//   row_loss[BN] @ 4*BN
//   cand[BN*cap] @ 5*BN
struct WS {
    uint32_t* cnt; uint32_t* done; int* pos; float* ps; float* row_loss; uint32_t* cand;
};
static inline WS ws_layout(void* d_ws) {
    uint32_t* p = (uint32_t*)d_ws;
    WS w;
    w.cnt = p; w.done = p + BN; w.pos = (int*)(p + 2 * BN);
    w.ps = (float*)(p + 3 * BN); w.row_loss = (float*)(p + 4 * BN);
    w.cand = p + 5 * BN;
    return w;
}

// ---------------- Kernel 1: candidate gen (threefry) + target scan ----------
// Verbatim from the R5-verified kernel (147us wall, VALUBusy 82%).
// blocks [0, BN): target scan, one row each.
// blocks [BN, BN + BN*SEGS): threefry over one row segment, 4 chains in
// flight, candidates staged in LDS and flushed once per block.
__global__ __launch_bounds__(256) void gen_kernel(
    const float* __restrict__ input, const float* __restrict__ target,
    uint32_t* __restrict__ cnt, uint32_t* __restrict__ cand,
    int* __restrict__ pos_out, float* __restrict__ ps_out,
    uint32_t thr, int cap)
{
    const int tid = threadIdx.x;
    if (blockIdx.x < BN) {
        // ---- target scan role ----
        const int row = blockIdx.x;
        const size_t base = (size_t)row * YN;
        __shared__ volatile int s_pos;
        if (tid == 0) s_pos = -1;
        __syncthreads();
        const float4* t4 = (const float4*)(target + base);
        for (int j4 = tid; j4 < YN / 4; j4 += 256) {
            if (s_pos >= 0) break;               // benign racy early-exit
            float4 v = t4[j4];
            int c0 = 4 * j4;
            if (v.x != 0.0f) s_pos = c0;
            if (v.y != 0.0f) s_pos = c0 + 1;
            if (v.z != 0.0f) s_pos = c0 + 2;
            if (v.w != 0.0f) s_pos = c0 + 3;
        }
        __syncthreads();
        if (tid == 0) {
            int p = s_pos;
            pos_out[row] = p;
            ps_out[row] = input[base + p];
        }
        return;
    }
    // ---- threefry role: 24 strides of 256 (=6144) + tail of 106 ----
    const int b = blockIdx.x - BN;
    const int row = b >> 3;                      // b / SEGS
    const int seg = b & 7;                       // b % SEGS
    const uint32_t base32 = (uint32_t)row * YN;
    const int start = seg * SEGLEN;

    __shared__ uint32_t s_buf[LCAP];
    __shared__ uint32_t s_cnt;
    __shared__ uint32_t s_base;
    if (tid == 0) s_cnt = 0;
    __syncthreads();

    int col = start + tid;
    uint32_t cb = base32 + (uint32_t)col;        // counter for chain 0
    for (int k = 0; k < 6; ++k) {
        uint32_t b0 = tf_core(cb + 42u);
        uint32_t b1 = tf_core(cb + 298u);        // 256 + 42
        uint32_t b2 = tf_core(cb + 554u);        // 512 + 42
        uint32_t b3 = tf_core(cb + 810u);        // 768 + 42
        // pack (keyhi, col): bits < 2^25 -> (bits>>9) < 2^16; col < 2^16.
        if (b0 < thr) {
            uint32_t i = atomicAdd(&s_cnt, 1u);
            if (i < LCAP) s_buf[i] = ((b0 >> 9) << 16) | (uint32_t)col;
        }
        if (b1 < thr) {
            uint32_t i = atomicAdd(&s_cnt, 1u);
            if (i < LCAP) s_buf[i] = ((b1 >> 9) << 16) | (uint32_t)(col + 256);
        }
        if (b2 < thr) {
            uint32_t i = atomicAdd(&s_cnt, 1u);
            if (i < LCAP) s_buf[i] = ((b2 >> 9) << 16) | (uint32_t)(col + 512);
        }
        if (b3 < thr) {
            uint32_t i = atomicAdd(&s_cnt, 1u);
            if (i < LCAP) s_buf[i] = ((b3 >> 9) << 16) | (uint32_t)(col + 768);
        }
        col += 1024; cb += 1024u;
    }
    if (tid < SEGLEN - 6144) {                   // tail: 106 cols
        uint32_t bt = tf_core(cb + 42u);
        if (bt < thr) {
            uint32_t i = atomicAdd(&s_cnt, 1u);
            if (i < LCAP) s_buf[i] = ((bt >> 9) << 16) | (uint32_t)col;
        }
    }
    __syncthreads();

    // ---- flush: one global atomic reserves a chunk; coalesced copy ----
    const uint32_t tot = s_cnt;
    if (tid == 0) {
        if (tot > LCAP) {
            // unreachable statistically; force row fallback, publish nothing
            atomicAdd(cnt + row, 1u << 20);
            s_base = 0xFFFFFFFFu;
        } else {
            s_base = atomicAdd(cnt + row, tot);
        }
    }
    __syncthreads();
    const uint32_t base_ = s_base;
    if (base_ != 0xFFFFFFFFu) {
        uint32_t* mycand = cand + (size_t)row * (size_t)cap;
        for (uint32_t i = tid; i < tot; i += 256) {
            uint32_t gi = base_ + i;
            if (gi < (uint32_t)cap) mycand[gi] = s_buf[i];
        }
    }
}

// ---------------- Kernel 2: block-per-row resolve + fallback + reduce -------
// grid = BN blocks of 256 (4x the gather MLP of the R5 wave-per-row finish).
__global__ __launch_bounds__(256) void finish_kernel(
    const float* __restrict__ input, const uint32_t* __restrict__ cnt,
    const uint32_t* __restrict__ cand, const int* __restrict__ pos_,
    const float* __restrict__ ps_, const int* __restrict__ mt_ptr,
    float* __restrict__ row_loss, uint32_t* __restrict__ done,
    float* __restrict__ out, int cap)
{
    const int tid = threadIdx.x;
    const int row = blockIdx.x;
    const int pos = pos_[row];
    const float ps = ps_[row];
    const float* rowp = input + (size_t)row * YN;
    const uint32_t n = cnt[row];
    const uint32_t mt = (uint32_t)mt_ptr[0];

    __shared__ uint32_t s_u32[256];
    __shared__ uint64_t s_u64[256];
    __shared__ float s_red[256];
    __shared__ uint32_t s_tkt;

    bool fb = (n > (uint32_t)cap);

    if (!fb) {
        const uint32_t* cl = cand + (size_t)row * (size_t)cap;
        uint32_t mk = 0xFFFFFFFFu;           // unreachable: low16 real <= 49999
        for (uint32_t i = tid; i < n; i += 256) {
            uint32_t e = cl[i];
            int col = (int)(e & 0xFFFFu);
            if (col != pos) {
                float s = rowp[col];
                if ((1.0f + s) - ps >= 0.0f) mk = (e < mk) ? e : mk;
            }
        }
        s_u32[tid] = mk;
        __syncthreads();
        for (int st = 128; st > 0; st >>= 1) {
            if (tid < st) { uint32_t o = s_u32[tid + st]; if (o < s_u32[tid]) s_u32[tid] = o; }
            __syncthreads();
        }
        mk = s_u32[0];
        __syncthreads();
        if (mk == 0xFFFFFFFFu) {
            fb = true;          // first violator not in list (or none at all)
        } else {
            // rank = #{candidates: key < mk, col != pos}; all keys < mk are
            // below THR, hence in the list -> exact.
            uint32_t cc = 0;
            for (uint32_t i = tid; i < n; i += 256) {
                uint32_t e = cl[i];
                int col = (int)(e & 0xFFFFu);
                cc += ((e < mk) && (col != pos)) ? 1u : 0u;
            }
            s_u32[tid] = cc;
            __syncthreads();
            for (int st = 128; st > 0; st >>= 1) {
                if (tid < st) s_u32[tid] += s_u32[tid + st];
                __syncthreads();
            }
            if (tid == 0) {
                uint32_t rank = s_u32[0];
                float loss = 0.0f;
                if (rank < mt) {
                    int cstar = (int)(mk & 0xFFFFu);
                    float ns = rowp[cstar];
                    float nt = (float)(rank + 1u);
                    loss = logf(floorf(49999.0f / nt)) * ((1.0f - ps) + ns);
                }
                row_loss[row] = loss;
            }
            __syncthreads();
        }
    }
    if (fb) {
        // block-wide full scan (rare). 64-bit key (keyhi23 << 16 | col).
        const uint32_t cb0 = (uint32_t)row * (uint32_t)YN + 42u;
        uint64_t mk64 = ~0ull;
        for (int col = tid; col < YN; col += 256) {
            uint32_t bits = tf_core(cb0 + (uint32_t)col);
            uint64_t key = ((uint64_t)(bits >> 9) << 16) | (uint32_t)col;
            float m = (1.0f + rowp[col]) - ps;
            if ((m >= 0.0f) && (col != pos) && (key < mk64)) mk64 = key;
        }
        s_u64[tid] = mk64;
        __syncthreads();
        for (int st = 128; st > 0; st >>= 1) {
            if (tid < st) { uint64_t o = s_u64[tid + st]; if (o < s_u64[tid]) s_u64[tid] = o; }
            __syncthreads();
        }
        const uint64_t kstar = s_u64[0];
        __syncthreads();
        if (kstar == ~0ull) {
            if (tid == 0) row_loss[row] = 0.0f;
        } else {
            uint32_t cc = 0;
            for (int col = tid; col < YN; col += 256) {
                uint32_t bits = tf_core(cb0 + (uint32_t)col);
                uint64_t key = ((uint64_t)(bits >> 9) << 16) | (uint32_t)col;
                cc += ((key < kstar) && (col != pos)) ? 1u : 0u;
            }
            s_u32[tid] = cc;
            __syncthreads();
            for (int st = 128; st > 0; st >>= 1) {
                if (tid < st) s_u32[tid] += s_u32[tid + st];
                __syncthreads();
            }
            if (tid == 0) {
                uint32_t rank = s_u32[0];
                float fl = 0.0f;
                if (rank < mt) {
                    int cstar = (int)(kstar & 0xFFFFull);
                    float ns = rowp[cstar];
                    float nt = (float)(rank + 1u);
                    fl = logf(floorf(49999.0f / nt)) * ((1.0f - ps) + ns);
                }
                row_loss[row] = fl;
            }
        }
        __syncthreads();
    }

    // ---- done-ticket: last block reduces row_loss in EXACT original order --
    if (tid == 0) {
        __threadfence();                     // release row_loss[row] (4B dirty)
        s_tkt = atomicAdd(done, 1u);
    }
    __syncthreads();
    if (s_tkt != (uint32_t)(BN - 1)) return;

    __threadfence();                         // acquire all row_loss
    float acc = 0.0f;
    for (int i = tid; i < BN; i += 256) acc += row_loss[i];
    s_red[tid] = acc;
    __syncthreads();
    for (int st = 128; st > 0; st >>= 1) {
        if (tid < st) s_red[tid] += s_red[tid + st];
        __syncthreads();
    }
    if (tid == 0) out[0] = s_red[0];
}

extern "C" void kernel_launch(void* const* d_in, const int* in_sizes, int n_in,
                              void* d_out, int out_size, void* d_ws, size_t ws_size,
                              hipStream_t stream) {
    const float* input  = (const float*)d_in[0];
    const float* target = (const float*)d_in[1];
    const int*   mt     = (const int*)d_in[2];
    float* out = (float*)d_out;
    WS w = ws_layout(d_ws);

    // big path: THR=2^25 (E~390 cand/row, CAP 1024) needs ~4.2 MB of ws;
    // guard against a small workspace with the verified legacy sizing.
    const size_t need_big = (size_t)(5 * BN) * 4 + (size_t)BN * CAP_BIG * 4;
    uint32_t thr; int cap;
    if (ws_size >= need_big) { thr = 1u << 25; cap = CAP_BIG; }
    else                     { thr = 1u << 23; cap = CAP_SMALL; }

    // zero cnt + done (harness poisons ws with 0xAA before every launch)
    hipMemsetAsync(d_ws, 0, 2 * BN * sizeof(uint32_t), stream);

    gen_kernel<<<BN + BN * SEGS, 256, 0, stream>>>(
        input, target, w.cnt, w.cand, w.pos, w.ps, thr, cap);
    finish_kernel<<<BN, 256, 0, stream>>>(
        input, w.cnt, w.cand, w.pos, w.ps, mt, w.row_loss, w.done, out, cap);
}